// Round 13
// baseline (492.845 us; speedup 1.0000x reference)
//
#include <hip/hip_runtime.h>
#include <hip/hip_fp16.h>

typedef _Float16 half8  __attribute__((ext_vector_type(8)));
typedef _Float16 half4s __attribute__((ext_vector_type(4)));
typedef _Float16 half2v __attribute__((ext_vector_type(2)));
typedef float    float4v __attribute__((ext_vector_type(4)));

namespace {
constexpr int N_NODES = 50000;
constexpr int N_EDGES = 400000;
constexpr int MUL0 = 16;
constexpr int MUL1 = 8;
constexpr int DIM  = 40;
constexpr int RMLP = 64;
constexpr int WNUM = 576;
constexpr int GE   = 256;
constexpr int NGROUP = (N_EDGES + GE - 1) / GE;
constexpr int GRID = 256;
constexpr int WST = 80, AST = 80, FST = 56;
constexpr int OFF_ACT  = 92160;
constexpr int OFF_FEAT = 133120;
constexpr int OFF_RCV  = 161792;
constexpr int LDS_BYTES = 162816;
// CSR workspace layout (bytes)
constexpr size_t MSG_OFF    = 0;                         // [400000][40] f16 = 32,000,000
constexpr size_t PERM_OFF   = 32000000;                  // [400000] i32
constexpr size_t ROWPTR_OFF = 33600000;                  // [50001] i32 (padded)
constexpr size_t CNT_OFF    = 33800064;                  // [50000] i32
constexpr size_t CUR_OFF    = 34000064;                  // [50000] i32
constexpr size_t CSR_REQ    = 34200064;
constexpr float C_N0 = 0.2041241452319315f;
constexpr float C_NV = 0.3535533905932738f * 0.5773502691896258f;
constexpr float C_INV3 = 0.5773502691896258f;
constexpr float C_SQRT3 = 1.7320508075688772f;
}

#define MFMA16(a, b, c) __builtin_amdgcn_mfma_f32_16x16x32_f16((a), (b), (c), 0, 0, 0)

__device__ inline void h2_atomic_add(__half2* addr, __half2 val) {
#if __has_builtin(__builtin_amdgcn_flat_atomic_fadd_v2f16)
    half2v v = *reinterpret_cast<half2v*>(&val);
    (void)__builtin_amdgcn_flat_atomic_fadd_v2f16(
        reinterpret_cast<half2v*>(addr), v);
#else
    unsigned int* ai = reinterpret_cast<unsigned int*>(addr);
    unsigned int old = *ai, assumed;
    do {
        assumed = old;
        __half2 cur = *reinterpret_cast<__half2*>(&assumed);
        __half2 sum = __hadd2(cur, val);
        unsigned int nv = *reinterpret_cast<unsigned int*>(&sum);
        old = atomicCAS(ai, assumed, nv);
    } while (old != assumed);
#endif
}

// ===================== CSR build kernels =====================
__global__ __launch_bounds__(256) void hist_k(const int* __restrict__ ei,
                                              int* __restrict__ cnt) {
    const int e = blockIdx.x * 256 + threadIdx.x;
    if (e < N_EDGES) atomicAdd(&cnt[ei[N_EDGES + e]], 1);
}

__global__ __launch_bounds__(1024) void scan_k(const int* __restrict__ cnt,
                                               int* __restrict__ rowptr) {
    __shared__ int s[1024];
    const int t = threadIdx.x;
    constexpr int CH = 49;                 // 1024*49 = 50176 >= 50000
    const int b0 = t * CH;
    int sum = 0;
    for (int i = 0; i < CH; ++i) {
        const int idx = b0 + i;
        if (idx < N_NODES) sum += cnt[idx];
    }
    s[t] = sum;
    __syncthreads();
    for (int o = 1; o < 1024; o <<= 1) {   // Hillis-Steele inclusive
        const int x = (t >= o) ? s[t - o] : 0;
        __syncthreads();
        s[t] += x;
        __syncthreads();
    }
    int run = s[t] - sum;                  // exclusive base
    for (int i = 0; i < CH; ++i) {
        const int idx = b0 + i;
        if (idx < N_NODES) { rowptr[idx] = run; run += cnt[idx]; }
    }
    if (t == 0) rowptr[N_NODES] = N_EDGES;
}

__global__ __launch_bounds__(256) void fill_k(const int* __restrict__ ei,
                                              const int* __restrict__ rowptr,
                                              int* __restrict__ cursor,
                                              int* __restrict__ perm) {
    const int e = blockIdx.x * 256 + threadIdx.x;
    if (e < N_EDGES) {
        const int r = ei[N_EDGES + e];
        const int pos = rowptr[r] + atomicAdd(&cursor[r], 1);
        perm[pos] = e;
    }
}

// ===================== CSR edge kernel: messages, no atomics =====================
__global__ __launch_bounds__(512, 1) void edge_msg(
    const float* __restrict__ h,
    const int*   __restrict__ ei,
    const float* __restrict__ evec,
    const float* __restrict__ elen,
    const float* __restrict__ w1,
    const float* __restrict__ b1,
    const float* __restrict__ w2,
    const float* __restrict__ b2,
    _Float16*    __restrict__ msg)   // [N_EDGES][40] f16
{
    extern __shared__ char smem[];
    _Float16* w2L  = (_Float16*)smem;
    _Float16* actL = (_Float16*)(smem + OFF_ACT);
    _Float16* featL= (_Float16*)(smem + OFF_FEAT);

    const int t = threadIdx.x;
    for (int i = t; i < RMLP * WNUM; i += 512) {
        const int r = i / WNUM;
        const int j = i - r * WNUM;
        w2L[j * WST + r] = (_Float16)w2[i];
    }

    const int lane = t & 63, wid = t >> 6;
    const int l15 = lane & 15, lg = lane >> 4;
    const int usel = lg >> 1;

    for (int g = blockIdx.x; g < NGROUP; g += GRID) {
        const int base = g * GE;
        const int cntg = (N_EDGES - base < GE) ? (N_EDGES - base) : GE;

        // ---- P0a: feats (float4 gather) + act ----
        {
            const int el = t >> 1, q = t & 1;
            _Float16* fr = featL + el * FST;
            if (el < cntg) {
                const int eg = base + el;
                const int snd = ei[eg];
                const float4v* hp4 = (const float4v*)(h + (long)snd * DIM);
#pragma unroll
                for (int i = 0; i < 5; ++i) {
                    const float4v v = hp4[q * 5 + i];
#pragma unroll
                    for (int k = 0; k < 4; ++k)
                        fr[q * 20 + 4 * i + k] = (_Float16)v[k];
                }
                if (q == 0) {
                    const float v0 = evec[3 * eg + 0];
                    const float v1 = evec[3 * eg + 1];
                    const float v2 = evec[3 * eg + 2];
                    const float rinv = rsqrtf(v0 * v0 + v1 * v1 + v2 * v2) * C_SQRT3;
                    fr[40] = (_Float16)(v0 * rinv);
                    fr[41] = (_Float16)(v1 * rinv);
                    fr[42] = (_Float16)(v2 * rinv);
                }
                const float len = elen[eg];
#pragma unroll
                for (int i = 0; i < 4; ++i) {
                    half8 av;
#pragma unroll
                    for (int j2 = 0; j2 < 8; ++j2) {
                        const int r = q * 32 + i * 8 + j2;
                        const float tv = fmaf(len, w1[r], b1[r]);
                        av[j2] = (_Float16)(tv / (1.0f + __expf(-tv)));
                    }
                    *(half8*)&actL[el * AST + q * 32 + i * 8] = av;
                }
            } else {
                const half8 z = {};
#pragma unroll
                for (int i = 0; i < 20; ++i) fr[q * 20 + i] = (_Float16)0.f;
                if (q == 0) { fr[40] = fr[41] = fr[42] = (_Float16)0.f; }
#pragma unroll
                for (int i = 0; i < 4; ++i)
                    *(half8*)&actL[el * AST + q * 32 + i * 8] = z;
            }
        }
        __syncthreads();

        // ---- P0b: dot ----
        {
            const int el = t >> 1;
            const int ub = (t & 1) * 4;
            const _Float16* fr = featL + el * FST;
            const float s0 = (float)fr[40], s1 = (float)fr[41], s2 = (float)fr[42];
#pragma unroll
            for (int j2 = 0; j2 < 4; ++j2) {
                const int u = ub + j2;
                const float d = (float)fr[16 + 3 * u + 0] * s0
                              + (float)fr[16 + 3 * u + 1] * s1
                              + (float)fr[16 + 3 * u + 2] * s2;
                featL[el * FST + 44 + u] = (_Float16)(C_INV3 * d);
            }
        }
        __syncthreads();

        // ---- MFMA + contraction + message store ----
        {
            const int et0 = wid * 2;
            half8 B[2][2];
#pragma unroll
            for (int tt = 0; tt < 2; ++tt)
#pragma unroll
                for (int s = 0; s < 2; ++s)
                    B[tt][s] = *(const half8*)&actL[((et0 + tt) * 16 + l15) * AST + s * 32 + lg * 8];

            const float4v zz = {0.f, 0.f, 0.f, 0.f};
            float4v os0 = zz, os1 = zz;
            float4v t30 = zz, t31 = zz;
            float4v t4a0 = zz, t4a1 = zz, t4a2 = zz;
            float4v t4b0 = zz, t4b1 = zz, t4b2 = zz;

            const _Float16* fA = featL + ((et0 + 0) * 16 + l15) * FST;
            const _Float16* fB = featL + ((et0 + 1) * 16 + l15) * FST;

#pragma unroll
            for (int jp = 0; jp < 8; ++jp) {
                const half2v hA = *(const half2v*)&fA[2 * jp];
                const half2v hB = *(const half2v*)&fB[2 * jp];
#pragma unroll
                for (int h2 = 0; h2 < 2; ++h2) {
                    const int jt = 2 * jp + h2;
                    const float4v binit = *(const float4v*)&b2[jt * 16 + lg * 4];
                    const _Float16* wr = &w2L[(jt * 16 + l15) * WST];
                    const half8 w0 = *(const half8*)&wr[lg * 8];
                    const half8 w1v = *(const half8*)&wr[32 + lg * 8];
                    float4v d0 = MFMA16(w0, B[0][0], binit); d0 = MFMA16(w1v, B[0][1], d0);
                    float4v d1 = MFMA16(w0, B[1][0], binit); d1 = MFMA16(w1v, B[1][1], d1);
                    os0 += (float)hA[h2] * d0;
                    os1 += (float)hB[h2] * d1;
                }
            }
#pragma unroll
            for (int jp = 0; jp < 4; ++jp) {
                const half2v hA = *(const half2v*)&fA[44 + 2 * jp];
                const half2v hB = *(const half2v*)&fB[44 + 2 * jp];
#pragma unroll
                for (int h2 = 0; h2 < 2; ++h2) {
                    const int jt = 16 + 2 * jp + h2;
                    const float4v binit = *(const float4v*)&b2[jt * 16 + lg * 4];
                    const _Float16* wr = &w2L[(jt * 16 + l15) * WST];
                    const half8 w0 = *(const half8*)&wr[lg * 8];
                    const half8 w1v = *(const half8*)&wr[32 + lg * 8];
                    float4v d0 = MFMA16(w0, B[0][0], binit); d0 = MFMA16(w1v, B[0][1], d0);
                    float4v d1 = MFMA16(w0, B[1][0], binit); d1 = MFMA16(w1v, B[1][1], d1);
                    os0 += (float)hA[h2] * d0;
                    os1 += (float)hB[h2] * d1;
                }
            }
#pragma unroll
            for (int jt = 24; jt < 32; ++jt) {
                const int u = 2 * (jt - 24) + usel;
                const float4v binit = *(const float4v*)&b2[jt * 16 + lg * 4];
                const _Float16* wr = &w2L[(jt * 16 + l15) * WST];
                const half8 w0 = *(const half8*)&wr[lg * 8];
                const half8 w1v = *(const half8*)&wr[32 + lg * 8];
                float4v d0 = MFMA16(w0, B[0][0], binit); d0 = MFMA16(w1v, B[0][1], d0);
                float4v d1 = MFMA16(w0, B[1][0], binit); d1 = MFMA16(w1v, B[1][1], d1);
                t30 += (float)fA[u] * d0;
                t31 += (float)fB[u] * d1;
            }
#pragma unroll
            for (int jt = 32; jt < 36; ++jt) {
                const int u = 2 * (jt - 32) + usel;
                const float4v binit = *(const float4v*)&b2[jt * 16 + lg * 4];
                const _Float16* wr = &w2L[(jt * 16 + l15) * WST];
                const half8 w0 = *(const half8*)&wr[lg * 8];
                const half8 w1v = *(const half8*)&wr[32 + lg * 8];
                float4v d0 = MFMA16(w0, B[0][0], binit); d0 = MFMA16(w1v, B[0][1], d0);
                float4v d1 = MFMA16(w0, B[1][0], binit); d1 = MFMA16(w1v, B[1][1], d1);
                t4a0 += (float)fA[16 + 3 * u + 0] * d0;
                t4a1 += (float)fA[16 + 3 * u + 1] * d0;
                t4a2 += (float)fA[16 + 3 * u + 2] * d0;
                t4b0 += (float)fB[16 + 3 * u + 0] * d1;
                t4b1 += (float)fB[16 + 3 * u + 1] * d1;
                t4b2 += (float)fB[16 + 3 * u + 2] * d1;
            }

#pragma unroll
            for (int r = 0; r < 4; ++r) {
                t30[r] += __shfl_xor(t30[r], 32);
                t31[r] += __shfl_xor(t31[r], 32);
                t4a0[r] += __shfl_xor(t4a0[r], 32);
                t4a1[r] += __shfl_xor(t4a1[r], 32);
                t4a2[r] += __shfl_xor(t4a2[r], 32);
                t4b0[r] += __shfl_xor(t4b0[r], 32);
                t4b1[r] += __shfl_xor(t4b1[r], 32);
                t4b2[r] += __shfl_xor(t4b2[r], 32);
            }

            // ---- store message (coalesced-ish plain stores, no atomics) ----
#pragma unroll
            for (int tt = 0; tt < 2; ++tt) {
                const int el = (et0 + tt) * 16 + l15;
                if (el < cntg) {
                    _Float16* mr = msg + (long)(base + el) * DIM;
                    const float4v& os = tt ? os1 : os0;
                    half4s o;
#pragma unroll
                    for (int r = 0; r < 4; ++r) o[r] = (_Float16)(C_N0 * os[r]);
                    *(half4s*)&mr[lg * 4] = o;
                    if (lg < 2) {
                        const _Float16* fr = featL + el * FST;
                        const float s0 = (float)fr[40], s1 = (float)fr[41], s2 = (float)fr[42];
                        const float4v& t3 = tt ? t31 : t30;
                        const float4v& x0 = tt ? t4b0 : t4a0;
                        const float4v& x1 = tt ? t4b1 : t4a1;
                        const float4v& x2 = tt ? t4b2 : t4a2;
                        float vv[12];
#pragma unroll
                        for (int r = 0; r < 4; ++r) {
                            vv[3 * r + 0] = C_NV * (x0[r] + t3[r] * s0);
                            vv[3 * r + 1] = C_NV * (x1[r] + t3[r] * s1);
                            vv[3 * r + 2] = C_NV * (x2[r] + t3[r] * s2);
                        }
#pragma unroll
                        for (int b4 = 0; b4 < 3; ++b4) {
                            half4s pv;
#pragma unroll
                            for (int k = 0; k < 4; ++k) pv[k] = (_Float16)vv[4 * b4 + k];
                            *(half4s*)&mr[16 + 12 * lg + 4 * b4] = pv;
                        }
                    }
                }
            }
        }
        __syncthreads();
    }
}

// ===================== CSR node gather: f32 reduce + gate + residual =====================
__global__ __launch_bounds__(256) void node_gather(
    const float* __restrict__ h,
    const float* __restrict__ gw,
    const float* __restrict__ gb,
    const _Float16* __restrict__ msg,
    const int*   __restrict__ perm,
    const int*   __restrict__ rowptr,
    float*       __restrict__ out)
{
    const int t = threadIdx.x;
    const int n = blockIdx.x * 64 + (t >> 2);
    const int p = t & 3;                  // channel quarter: ch p*10..p*10+9
    if (n >= N_NODES) return;
    const int beg = rowptr[n], end = rowptr[n + 1];

    float acc[10] = {};
    for (int i = beg; i < end; ++i) {
        const int e = perm[i];
        const _Float16* mr = msg + (long)e * DIM + p * 10;
#pragma unroll
        for (int c = 0; c < 5; ++c) {
            const half2v v = *(const half2v*)&mr[2 * c];
            acc[2 * c]     += (float)v[0];
            acc[2 * c + 1] += (float)v[1];
        }
    }

    const float* hp = h + (long)n * DIM;
    float* op = out + (long)n * DIM;
    float hs[16];
#pragma unroll
    for (int u = 0; u < 16; ++u) hs[u] = hp[u];

#pragma unroll
    for (int k = 0; k < 10; ++k) {
        const int ch = p * 10 + k;
        if (ch < MUL0) {
            op[ch] = hp[ch] + acc[k];
        } else {
            const int j = ch - MUL0;
            float a = gb[j];
#pragma unroll
            for (int u = 0; u < 16; ++u) a = fmaf(hs[u], gw[u * 24 + j], a);
            const float gt = 1.0f / (1.0f + __expf(-a));
            op[ch] = fmaf(acc[k], gt, hp[ch]);
        }
    }
}

// ===================== Fallback path (byte-identical v3) =====================
__global__ __launch_bounds__(512, 1) void edge_fused3(
    const float* __restrict__ h,
    const int*   __restrict__ ei,
    const float* __restrict__ evec,
    const float* __restrict__ elen,
    const float* __restrict__ w1,
    const float* __restrict__ b1,
    const float* __restrict__ w2,
    const float* __restrict__ b2,
    __half2*     __restrict__ agg2)
{
    extern __shared__ char smem[];
    _Float16* w2L  = (_Float16*)smem;
    _Float16* actL = (_Float16*)(smem + OFF_ACT);
    _Float16* featL= (_Float16*)(smem + OFF_FEAT);
    int*      rcvL = (int*)(smem + OFF_RCV);

    const int t = threadIdx.x;
    for (int i = t; i < RMLP * WNUM; i += 512) {
        const int r = i / WNUM;
        const int j = i - r * WNUM;
        w2L[j * WST + r] = (_Float16)w2[i];
    }

    const int lane = t & 63, wid = t >> 6;
    const int l15 = lane & 15, lg = lane >> 4;
    const int usel = lg >> 1;

    __half2 pOS[2][2];
    __half2 pV[2][6];
    int pR[2] = {0, 0};
    int pValid[2] = {0, 0};
    bool havePrev = false;

    for (int g = blockIdx.x; g < NGROUP; g += GRID) {
        if (havePrev) {
#pragma unroll
            for (int tt = 0; tt < 2; ++tt) {
                if (pValid[tt]) {
                    __half2* a2 = agg2 + (long)pR[tt] * 20;
                    h2_atomic_add(a2 + lg * 2 + 0, pOS[tt][0]);
                    h2_atomic_add(a2 + lg * 2 + 1, pOS[tt][1]);
                    if (lg < 2) {
#pragma unroll
                        for (int r2 = 0; r2 < 6; ++r2)
                            h2_atomic_add(a2 + 8 + 6 * lg + r2, pV[tt][r2]);
                    }
                }
            }
        }

        const int base = g * GE;
        const int cnt = (N_EDGES - base < GE) ? (N_EDGES - base) : GE;
        {
            const int el = t >> 1, q = t & 1;
            _Float16* fr = featL + el * FST;
            if (el < cnt) {
                const int eg = base + el;
                const int snd = ei[eg];
                const float* hp = h + (long)snd * DIM;
#pragma unroll
                for (int i = 0; i < 20; ++i)
                    fr[q * 20 + i] = (_Float16)hp[q * 20 + i];
                if (q == 0) {
                    rcvL[el] = ei[N_EDGES + eg];
                    const float v0 = evec[3 * eg + 0];
                    const float v1 = evec[3 * eg + 1];
                    const float v2 = evec[3 * eg + 2];
                    const float rinv = rsqrtf(v0 * v0 + v1 * v1 + v2 * v2) * C_SQRT3;
                    fr[40] = (_Float16)(v0 * rinv);
                    fr[41] = (_Float16)(v1 * rinv);
                    fr[42] = (_Float16)(v2 * rinv);
                }
                const float len = elen[eg];
#pragma unroll
                for (int i = 0; i < 4; ++i) {
                    half8 av;
#pragma unroll
                    for (int j2 = 0; j2 < 8; ++j2) {
                        const int r = q * 32 + i * 8 + j2;
                        const float tv = fmaf(len, w1[r], b1[r]);
                        av[j2] = (_Float16)(tv / (1.0f + __expf(-tv)));
                    }
                    *(half8*)&actL[el * AST + q * 32 + i * 8] = av;
                }
            } else {
                const half8 z = {};
#pragma unroll
                for (int i = 0; i < 20; ++i) fr[q * 20 + i] = (_Float16)0.f;
                if (q == 0) {
                    rcvL[el] = 0;
                    fr[40] = fr[41] = fr[42] = (_Float16)0.f;
                }
#pragma unroll
                for (int i = 0; i < 4; ++i)
                    *(half8*)&actL[el * AST + q * 32 + i * 8] = z;
            }
        }
        __syncthreads();
        {
            const int el = t >> 1;
            const int ub = (t & 1) * 4;
            const _Float16* fr = featL + el * FST;
            const float s0 = (float)fr[40], s1 = (float)fr[41], s2 = (float)fr[42];
#pragma unroll
            for (int j2 = 0; j2 < 4; ++j2) {
                const int u = ub + j2;
                const float d = (float)fr[16 + 3 * u + 0] * s0
                              + (float)fr[16 + 3 * u + 1] * s1
                              + (float)fr[16 + 3 * u + 2] * s2;
                featL[el * FST + 44 + u] = (_Float16)(C_INV3 * d);
            }
        }
        __syncthreads();
        {
            const int et0 = wid * 2;
            half8 B[2][2];
#pragma unroll
            for (int tt = 0; tt < 2; ++tt)
#pragma unroll
                for (int s = 0; s < 2; ++s)
                    B[tt][s] = *(const half8*)&actL[((et0 + tt) * 16 + l15) * AST + s * 32 + lg * 8];

            const float4v zz = {0.f, 0.f, 0.f, 0.f};
            float4v os0 = zz, os1 = zz;
            float4v t30 = zz, t31 = zz;
            float4v t4a0 = zz, t4a1 = zz, t4a2 = zz;
            float4v t4b0 = zz, t4b1 = zz, t4b2 = zz;

            const _Float16* fA = featL + ((et0 + 0) * 16 + l15) * FST;
            const _Float16* fB = featL + ((et0 + 1) * 16 + l15) * FST;

#pragma unroll
            for (int jp = 0; jp < 8; ++jp) {
                const half2v hA = *(const half2v*)&fA[2 * jp];
                const half2v hB = *(const half2v*)&fB[2 * jp];
#pragma unroll
                for (int h2 = 0; h2 < 2; ++h2) {
                    const int jt = 2 * jp + h2;
                    const float4v binit = *(const float4v*)&b2[jt * 16 + lg * 4];
                    const _Float16* wr = &w2L[(jt * 16 + l15) * WST];
                    const half8 w0 = *(const half8*)&wr[lg * 8];
                    const half8 w1v = *(const half8*)&wr[32 + lg * 8];
                    float4v d0 = MFMA16(w0, B[0][0], binit); d0 = MFMA16(w1v, B[0][1], d0);
                    float4v d1 = MFMA16(w0, B[1][0], binit); d1 = MFMA16(w1v, B[1][1], d1);
                    os0 += (float)hA[h2] * d0;
                    os1 += (float)hB[h2] * d1;
                }
            }
#pragma unroll
            for (int jp = 0; jp < 4; ++jp) {
                const half2v hA = *(const half2v*)&fA[44 + 2 * jp];
                const half2v hB = *(const half2v*)&fB[44 + 2 * jp];
#pragma unroll
                for (int h2 = 0; h2 < 2; ++h2) {
                    const int jt = 16 + 2 * jp + h2;
                    const float4v binit = *(const float4v*)&b2[jt * 16 + lg * 4];
                    const _Float16* wr = &w2L[(jt * 16 + l15) * WST];
                    const half8 w0 = *(const half8*)&wr[lg * 8];
                    const half8 w1v = *(const half8*)&wr[32 + lg * 8];
                    float4v d0 = MFMA16(w0, B[0][0], binit); d0 = MFMA16(w1v, B[0][1], d0);
                    float4v d1 = MFMA16(w0, B[1][0], binit); d1 = MFMA16(w1v, B[1][1], d1);
                    os0 += (float)hA[h2] * d0;
                    os1 += (float)hB[h2] * d1;
                }
            }
#pragma unroll
            for (int jt = 24; jt < 32; ++jt) {
                const int u = 2 * (jt - 24) + usel;
                const float4v binit = *(const float4v*)&b2[jt * 16 + lg * 4];
                const _Float16* wr = &w2L[(jt * 16 + l15) * WST];
                const half8 w0 = *(const half8*)&wr[lg * 8];
                const half8 w1v = *(const half8*)&wr[32 + lg * 8];
                float4v d0 = MFMA16(w0, B[0][0], binit); d0 = MFMA16(w1v, B[0][1], d0);
                float4v d1 = MFMA16(w0, B[1][0], binit); d1 = MFMA16(w1v, B[1][1], d1);
                t30 += (float)fA[u] * d0;
                t31 += (float)fB[u] * d1;
            }
#pragma unroll
            for (int jt = 32; jt < 36; ++jt) {
                const int u = 2 * (jt - 32) + usel;
                const float4v binit = *(const float4v*)&b2[jt * 16 + lg * 4];
                const _Float16* wr = &w2L[(jt * 16 + l15) * WST];
                const half8 w0 = *(const half8*)&wr[lg * 8];
                const half8 w1v = *(const half8*)&wr[32 + lg * 8];
                float4v d0 = MFMA16(w0, B[0][0], binit); d0 = MFMA16(w1v, B[0][1], d0);
                float4v d1 = MFMA16(w0, B[1][0], binit); d1 = MFMA16(w1v, B[1][1], d1);
                t4a0 += (float)fA[16 + 3 * u + 0] * d0;
                t4a1 += (float)fA[16 + 3 * u + 1] * d0;
                t4a2 += (float)fA[16 + 3 * u + 2] * d0;
                t4b0 += (float)fB[16 + 3 * u + 0] * d1;
                t4b1 += (float)fB[16 + 3 * u + 1] * d1;
                t4b2 += (float)fB[16 + 3 * u + 2] * d1;
            }
#pragma unroll
            for (int r = 0; r < 4; ++r) {
                t30[r] += __shfl_xor(t30[r], 32);
                t31[r] += __shfl_xor(t31[r], 32);
                t4a0[r] += __shfl_xor(t4a0[r], 32);
                t4a1[r] += __shfl_xor(t4a1[r], 32);
                t4a2[r] += __shfl_xor(t4a2[r], 32);
                t4b0[r] += __shfl_xor(t4b0[r], 32);
                t4b1[r] += __shfl_xor(t4b1[r], 32);
                t4b2[r] += __shfl_xor(t4b2[r], 32);
            }
#pragma unroll
            for (int tt = 0; tt < 2; ++tt) {
                const int el = (et0 + tt) * 16 + l15;
                pValid[tt] = (el < cnt);
                pR[tt] = rcvL[el];
                const float4v& os = tt ? os1 : os0;
                pOS[tt][0] = __floats2half2_rn(C_N0 * os[0], C_N0 * os[1]);
                pOS[tt][1] = __floats2half2_rn(C_N0 * os[2], C_N0 * os[3]);
                const _Float16* fr = featL + el * FST;
                const float s0 = (float)fr[40], s1 = (float)fr[41], s2 = (float)fr[42];
                const float4v& t3 = tt ? t31 : t30;
                const float4v& x0 = tt ? t4b0 : t4a0;
                const float4v& x1 = tt ? t4b1 : t4a1;
                const float4v& x2 = tt ? t4b2 : t4a2;
                float vv[12];
#pragma unroll
                for (int r = 0; r < 4; ++r) {
                    vv[3 * r + 0] = C_NV * (x0[r] + t3[r] * s0);
                    vv[3 * r + 1] = C_NV * (x1[r] + t3[r] * s1);
                    vv[3 * r + 2] = C_NV * (x2[r] + t3[r] * s2);
                }
#pragma unroll
                for (int r2 = 0; r2 < 6; ++r2)
                    pV[tt][r2] = __floats2half2_rn(vv[2 * r2], vv[2 * r2 + 1]);
            }
        }
        __syncthreads();
        havePrev = true;
    }

    if (havePrev) {
#pragma unroll
        for (int tt = 0; tt < 2; ++tt) {
            if (pValid[tt]) {
                __half2* a2 = agg2 + (long)pR[tt] * 20;
                h2_atomic_add(a2 + lg * 2 + 0, pOS[tt][0]);
                h2_atomic_add(a2 + lg * 2 + 1, pOS[tt][1]);
                if (lg < 2) {
#pragma unroll
                    for (int r2 = 0; r2 < 6; ++r2)
                        h2_atomic_add(a2 + 8 + 6 * lg + r2, pV[tt][r2]);
                }
            }
        }
    }
}

__global__ __launch_bounds__(256) void node_kernel2(
    const float* __restrict__ h,
    const float* __restrict__ gw,
    const float* __restrict__ gb,
    const __half2* __restrict__ agg2,
    float*       __restrict__ out)
{
    const int n = blockIdx.x * 256 + threadIdx.x;
    if (n >= N_NODES) return;
    const float* hp = h + (long)n * DIM;
    float* op = out + (long)n * DIM;
    const __half2* ar = agg2 + (long)n * 20;

    float ag[DIM];
#pragma unroll
    for (int i = 0; i < 20; ++i) {
        const float2 f = __half22float2(ar[i]);
        ag[2 * i] = f.x;
        ag[2 * i + 1] = f.y;
    }
    float hsv[MUL0];
#pragma unroll
    for (int u = 0; u < MUL0; ++u) hsv[u] = hp[u];
#pragma unroll
    for (int i = 0; i < MUL0; ++i) op[i] = hsv[i] + ag[i];
#pragma unroll 1
    for (int j = 0; j < 3 * MUL1; ++j) {
        float a = gb[j];
#pragma unroll
        for (int u = 0; u < MUL0; ++u) a = fmaf(hsv[u], gw[u * (3 * MUL1) + j], a);
        const float g = 1.0f / (1.0f + __expf(-a));
        op[MUL0 + j] = fmaf(ag[MUL0 + j], g, hp[MUL0 + j]);
    }
}

extern "C" void kernel_launch(void* const* d_in, const int* in_sizes, int n_in,
                              void* d_out, int out_size, void* d_ws, size_t ws_size,
                              hipStream_t stream)
{
    const float* h    = (const float*)d_in[0];
    const int*   ei   = (const int*)d_in[1];
    const float* evec = (const float*)d_in[2];
    const float* elen = (const float*)d_in[3];
    const float* w1   = (const float*)d_in[4];
    const float* b1   = (const float*)d_in[5];
    const float* w2   = (const float*)d_in[6];
    const float* b2   = (const float*)d_in[7];
    const float* gw   = (const float*)d_in[8];
    const float* gb   = (const float*)d_in[9];
    float* out = (float*)d_out;
    char* ws = (char*)d_ws;

    (void)hipFuncSetAttribute((const void*)edge_msg,
                              hipFuncAttributeMaxDynamicSharedMemorySize, LDS_BYTES);
    (void)hipFuncSetAttribute((const void*)edge_fused3,
                              hipFuncAttributeMaxDynamicSharedMemorySize, LDS_BYTES);

    if (ws_size >= CSR_REQ) {
        _Float16* msg  = (_Float16*)(ws + MSG_OFF);
        int* perm      = (int*)(ws + PERM_OFF);
        int* rowptr    = (int*)(ws + ROWPTR_OFF);
        int* cnt       = (int*)(ws + CNT_OFF);
        int* cursor    = (int*)(ws + CUR_OFF);

        (void)hipMemsetAsync(ws + CNT_OFF, 0, 400000, stream);  // cnt + cursor
        hist_k<<<(N_EDGES + 255) / 256, 256, 0, stream>>>(ei, cnt);
        scan_k<<<1, 1024, 0, stream>>>(cnt, rowptr);
        fill_k<<<(N_EDGES + 255) / 256, 256, 0, stream>>>(ei, rowptr, cursor, perm);
        edge_msg<<<GRID, 512, LDS_BYTES, stream>>>(
            h, ei, evec, elen, w1, b1, w2, b2, msg);
        node_gather<<<(N_NODES + 63) / 64, 256, 0, stream>>>(
            h, gw, gb, msg, perm, rowptr, out);
    } else {
        __half2* agg2 = (__half2*)d_ws;
        (void)hipMemsetAsync(d_ws, 0, (size_t)N_NODES * DIM * sizeof(__half), stream);
        edge_fused3<<<GRID, 512, LDS_BYTES, stream>>>(
            h, ei, evec, elen, w1, b1, w2, b2, agg2);
        node_kernel2<<<(N_NODES + 255) / 256, 256, 0, stream>>>(h, gw, gb, agg2, out);
    }
}